// Round 2
// baseline (441.083 us; speedup 1.0000x reference)
//
#include <hip/hip_runtime.h>

// LatentClassifier collapse (all f32 I/O):
//   All depth-loop layernorms act on singleton axes -> LN(x) == bias exactly.
//   => h = x + c[t],  c[t] = sum_i alpha_i*w2_i*(beta_i*R_i[t] + sgu_proj_b[i,t]) + b2_i
//      alpha_i = gelu(ln1_b[i,0]*cp1_w[i,0,0] + cp1_b[i,0]), beta_i = sgu_ln_b[i,0],
//      R_i[t] = rowsum(sgu_proj_w[i,t,:])  (beta_i == 0 with given inputs -> skipped)
//   out = (gelu((x+c) @ P^T + pooler_b)) @ cls_w^T + cls_b
//   c is per-column => (x+c)@P^T = x@P^T + d[s],  d[s] = sum_t c[t]*P[s,t]
// Inputs are FP32; no fp32 MFMA on CDNA4 -> convert x,P to bf16 once (into ws),
// then one 4096^3 bf16 MFMA GEMM + fused gelu/cls epilogue atomicAdd into d_out.

#define K_DIM 4096

typedef __bf16 bf16x8 __attribute__((ext_vector_type(8)));
typedef float f32x4 __attribute__((ext_vector_type(4)));

__device__ __forceinline__ ushort f2bf(float f) {
    unsigned int u = __float_as_uint(f);
    u = (u + 0x7fffu + ((u >> 16) & 1u)) >> 16;  // RTNE
    return (ushort)u;
}

__device__ __forceinline__ float gelu_exact(float x) {
    return 0.5f * x * (1.0f + erff(x * 0.70710678118654752440f));
}

__device__ __forceinline__ void gld16(const void* g, void* l) {
    __builtin_amdgcn_global_load_lds(
        (__attribute__((address_space(1))) void*)(g),
        (__attribute__((address_space(3))) void*)(l), 16, 0, 0);
}

// ---------- K0: f32 -> bf16 convert (8 elements/thread) -------------------------
__global__ __launch_bounds__(256) void cvt_kernel(const float* __restrict__ src,
                                                  ushort* __restrict__ dst) {
    int i = blockIdx.x * 256 + threadIdx.x;  // 8 floats each
    const float4* s4 = (const float4*)src + (size_t)i * 2;
    float4 a = s4[0], b = s4[1];
    union { ushort u[8]; uint4 v; } r;
    r.u[0] = f2bf(a.x); r.u[1] = f2bf(a.y); r.u[2] = f2bf(a.z); r.u[3] = f2bf(a.w);
    r.u[4] = f2bf(b.x); r.u[5] = f2bf(b.y); r.u[6] = f2bf(b.z); r.u[7] = f2bf(b.w);
    ((uint4*)dst)[i] = r.v;
}

// ---------- K1: R_i[t] = rowsum(sgu_proj_w[i,t,:]); 0 fast-path when beta==0 ----
__global__ __launch_bounds__(256) void rowsum_kernel(const float* __restrict__ proj_w,
                                                     const float* __restrict__ sgu_ln_b,
                                                     float* __restrict__ R) {
    int wid  = (blockIdx.x * 256 + threadIdx.x) >> 6;  // 0..8191 (= layer*4096 + t)
    int lane = threadIdx.x & 63;
    int layer = wid >> 12;
    float beta = sgu_ln_b[layer];
    if (beta == 0.0f) {  // wave-uniform; inputs identical every call
        if (lane == 0) R[wid] = 0.0f;
        return;
    }
    const float* pr = proj_w + (size_t)wid * K_DIM;
    float s = 0.0f;
    for (int it = 0; it < 16; ++it) {
        float4 pv = *(const float4*)&pr[it * 256 + lane * 4];
        s += pv.x + pv.y + pv.z + pv.w;
    }
#pragma unroll
    for (int m = 1; m < 64; m <<= 1) s += __shfl_xor(s, m);
    if (lane == 0) R[wid] = s;
}

// ---------- K2: c[t]; also init d_out[t] = cls_b --------------------------------
__global__ __launch_bounds__(256) void c_kernel(const float* __restrict__ ln1_b,
                                                const float* __restrict__ cp1_w,
                                                const float* __restrict__ cp1_b,
                                                const float* __restrict__ sgu_ln_b,
                                                const float* __restrict__ sgu_proj_b,
                                                const float* __restrict__ cp2_w,
                                                const float* __restrict__ cp2_b,
                                                const float* __restrict__ cls_b,
                                                const float* __restrict__ R,
                                                float* __restrict__ c,
                                                float* __restrict__ out) {
    int t = blockIdx.x * 256 + threadIdx.x;  // 0..4095
    float cv = 0.0f;
#pragma unroll
    for (int i = 0; i < 2; ++i) {
        // LN over singleton axis == its bias; u-channel (ch 0) of 1->2 conv + gelu
        float alpha = gelu_exact(ln1_b[i] * cp1_w[i * 2 + 0] + cp1_b[i * 2 + 0]);
        float beta  = sgu_ln_b[i];
        float v     = beta * R[i * 4096 + t] + sgu_proj_b[i * 4096 + t];
        cv += alpha * v * cp2_w[i] + cp2_b[i];
    }
    c[t]   = cv;
    out[t] = cls_b[0];  // d_out is poisoned before every call -> re-init here
}

// ---------- K3: e[s] = sum_t c[t]*P[s,t] + pooler_b[s]  (P is f32) --------------
__global__ __launch_bounds__(256) void e_kernel(const float* __restrict__ P,
                                                const float* __restrict__ c,
                                                const float* __restrict__ pooler_b,
                                                float* __restrict__ e) {
    int row  = blockIdx.x * 4 + (threadIdx.x >> 6);
    int lane = threadIdx.x & 63;
    const float* pr = P + (size_t)row * K_DIM;
    float s = 0.0f;
    for (int it = 0; it < 16; ++it) {
        int col = it * 256 + lane * 4;
        float4 pv = *(const float4*)&pr[col];
        s += pv.x * c[col] + pv.y * c[col + 1] + pv.z * c[col + 2] + pv.w * c[col + 3];
    }
#pragma unroll
    for (int m = 1; m < 64; m <<= 1) s += __shfl_xor(s, m);
    if (lane == 0) e[row] = s + pooler_b[row];
}

// ---------- K4: Y = x @ P^T (bf16 MFMA); fused gelu(Y+e)*cls_w row-reduce -------
// m97 structure: 128x128 tile, BK=32, 4 waves (2x2), 4x4 frags of 16x16x32 MFMA,
// global_load_lds width-16 staging (wave-uniform base + lane*16 LDS layout).
__global__ __launch_bounds__(256, 2) void gemm_kernel(const ushort* __restrict__ X,
                                                      const ushort* __restrict__ P,
                                                      const float* __restrict__ clsW,
                                                      const float* __restrict__ e,
                                                      float* __restrict__ accOut) {
    __shared__ __align__(16) ushort As[128 * 32];
    __shared__ __align__(16) ushort Bs[128 * 32];

    const int t = threadIdx.x;
    const int bCol = blockIdx.x, bRow = blockIdx.y;
    const int lane = t & 63, wv = t >> 6;
    const int g = lane >> 4, lo = lane & 15;
    const int wm = wv >> 1, wn = wv & 1;

    f32x4 zero4 = {0.f, 0.f, 0.f, 0.f};
    f32x4 acc[4][4];
#pragma unroll
    for (int mi = 0; mi < 4; ++mi)
#pragma unroll
        for (int ni = 0; ni < 4; ++ni) acc[mi][ni] = zero4;

    // staging: thread t loads 16B = 8 bf16; tile row = t/4, col = (t%4)*8
    const int sr = t >> 2;
    const int sc = (t & 3) * 8;
    const ushort* gA = X + (size_t)(bRow * 128 + sr) * K_DIM + sc;
    const ushort* gB = P + (size_t)(bCol * 128 + sr) * K_DIM + sc;
    char* lA = (char*)As + t * 16;
    char* lB = (char*)Bs + t * 16;

    for (int k0 = 0; k0 < K_DIM; k0 += 32) {
        gld16(gA, lA);
        gld16(gA + 64 * K_DIM, lA + 4096);
        gld16(gB, lB);
        gld16(gB + 64 * K_DIM, lB + 4096);
        gA += 32;
        gB += 32;
        __syncthreads();  // compiler emits vmcnt(0) drain before s_barrier

        bf16x8 af[4], bfr[4];
#pragma unroll
        for (int mi = 0; mi < 4; ++mi) {
            int row = wm * 64 + mi * 16 + lo;
            af[mi] = *(const bf16x8*)&As[row * 32 + g * 8];
        }
#pragma unroll
        for (int ni = 0; ni < 4; ++ni) {
            int col = wn * 64 + ni * 16 + lo;
            bfr[ni] = *(const bf16x8*)&Bs[col * 32 + g * 8];
        }
#pragma unroll
        for (int mi = 0; mi < 4; ++mi)
#pragma unroll
            for (int ni = 0; ni < 4; ++ni)
                acc[mi][ni] = __builtin_amdgcn_mfma_f32_16x16x32_bf16(af[mi], bfr[ni], acc[mi][ni], 0, 0, 0);
        __syncthreads();
    }

    // Epilogue: C/D layout col=lane&15, row=(lane>>4)*4+reg (m89-verified).
    int sColBase = bCol * 128 + wn * 64 + lo;
    float eb[4], cw[4];
#pragma unroll
    for (int ni = 0; ni < 4; ++ni) {
        int s = sColBase + ni * 16;
        eb[ni] = e[s];
        cw[ni] = clsW[s];
    }
#pragma unroll
    for (int mi = 0; mi < 4; ++mi) {
        int rowBase = bRow * 128 + wm * 64 + mi * 16 + g * 4;
#pragma unroll
        for (int r = 0; r < 4; ++r) {
            float sum = 0.0f;
#pragma unroll
            for (int ni = 0; ni < 4; ++ni) {
                float y = acc[mi][ni][r] + eb[ni];
                sum += gelu_exact(y) * cw[ni];
            }
            // reduce across the 16 lanes (bits 0..3) holding this row's 16 cols
            sum += __shfl_xor(sum, 1);
            sum += __shfl_xor(sum, 2);
            sum += __shfl_xor(sum, 4);
            sum += __shfl_xor(sum, 8);
            if (lo == 0) atomicAdd(&accOut[rowBase + r], sum);
        }
    }
}

extern "C" void kernel_launch(void* const* d_in, const int* in_sizes, int n_in,
                              void* d_out, int out_size, void* d_ws, size_t ws_size,
                              hipStream_t stream) {
    const float* x          = (const float*)d_in[0];
    const float* ln1_b      = (const float*)d_in[2];
    const float* cp1_w      = (const float*)d_in[3];
    const float* cp1_b      = (const float*)d_in[4];
    const float* sgu_ln_b   = (const float*)d_in[6];
    const float* sgu_proj_w = (const float*)d_in[7];
    const float* sgu_proj_b = (const float*)d_in[8];
    const float* cp2_w      = (const float*)d_in[9];
    const float* cp2_b      = (const float*)d_in[10];
    const float* pooler_w   = (const float*)d_in[11];
    const float* pooler_b   = (const float*)d_in[12];
    const float* cls_w      = (const float*)d_in[13];
    const float* cls_b      = (const float*)d_in[14];

    // ws layout: xb (32MB bf16) | pb (32MB bf16) | c(16KB) | e(16KB) | R(32KB)
    ushort* xb = (ushort*)d_ws;                  // 4096*4096 bf16
    ushort* pb = xb + (size_t)K_DIM * K_DIM;     // 4096*4096 bf16
    float*  fs = (float*)(pb + (size_t)K_DIM * K_DIM);
    float* c_buf = fs;
    float* e_buf = fs + 4096;
    float* R     = fs + 8192;
    float* out   = (float*)d_out;

    cvt_kernel<<<8192, 256, 0, stream>>>(x, xb);
    cvt_kernel<<<8192, 256, 0, stream>>>(pooler_w, pb);
    rowsum_kernel<<<2048, 256, 0, stream>>>(sgu_proj_w, sgu_ln_b, R);
    c_kernel<<<16, 256, 0, stream>>>(ln1_b, cp1_w, cp1_b, sgu_ln_b, sgu_proj_b,
                                     cp2_w, cp2_b, cls_b, R, c_buf, out);
    e_kernel<<<1024, 256, 0, stream>>>(pooler_w, c_buf, pooler_b, e_buf);
    gemm_kernel<<<dim3(32, 32), 256, 0, stream>>>(xb, pb, cls_w, e_buf, out);
}

// Round 3
// 412.344 us; speedup vs baseline: 1.0697x; 1.0697x over previous
//
#include <hip/hip_runtime.h>

// LatentClassifier collapse (all f32 I/O):
//   All depth-loop layernorms act on singleton axes -> LN(x) == bias exactly.
//   => h = x + c[t],  c[t] = sum_i alpha_i*w2_i*(beta_i*R_i[t] + sgu_proj_b[i,t]) + b2_i
//   out = (gelu((x+c) @ P^T + pooler_b)) @ cls_w^T + cls_b
//   c is per-column => (x+c)@P^T = x@P^T + d[s],  d[s] = sum_t c[t]*P[s,t]
// FP32 inputs, no fp32 MFMA -> one-pass convert x,P to bf16 in ws, then a
// 4096^3 bf16 MFMA GEMM with fused gelu/cls epilogue atomicAdd into d_out.
//
// R2: GEMM was LDS-bank-conflict-bound (SQ_LDS_BANK_CONFLICT = 1.678e7 =
// exactly 128 per block-iter; 8-way phase conflicts on ds_read_b128).
// Fix: XOR swizzle (slot = chunk ^ (row&7)) applied on the *global* side of
// global_load_lds staging, + BK=64 to halve barrier count.

#define K_DIM 4096

typedef __bf16 bf16x8 __attribute__((ext_vector_type(8)));
typedef float f32x4 __attribute__((ext_vector_type(4)));

__device__ __forceinline__ ushort f2bf(float f) {
    unsigned int u = __float_as_uint(f);
    u = (u + 0x7fffu + ((u >> 16) & 1u)) >> 16;  // RTNE
    return (ushort)u;
}

__device__ __forceinline__ float gelu_exact(float x) {
    return 0.5f * x * (1.0f + erff(x * 0.70710678118654752440f));
}

__device__ __forceinline__ void gld16(const void* g, void* l) {
    __builtin_amdgcn_global_load_lds(
        (__attribute__((address_space(1))) void*)(g),
        (__attribute__((address_space(3))) void*)(l), 16, 0, 0);
}

// ---------- K0: f32 -> bf16 convert (8 elements/thread) -------------------------
__global__ __launch_bounds__(256) void cvt_kernel(const float* __restrict__ src,
                                                  ushort* __restrict__ dst) {
    int i = blockIdx.x * 256 + threadIdx.x;  // 8 floats each
    const float4* s4 = (const float4*)src + (size_t)i * 2;
    float4 a = s4[0], b = s4[1];
    union { ushort u[8]; uint4 v; } r;
    r.u[0] = f2bf(a.x); r.u[1] = f2bf(a.y); r.u[2] = f2bf(a.z); r.u[3] = f2bf(a.w);
    r.u[4] = f2bf(b.x); r.u[5] = f2bf(b.y); r.u[6] = f2bf(b.z); r.u[7] = f2bf(b.w);
    ((uint4*)dst)[i] = r.v;
}

// ---------- K1: R_i[t] = rowsum(sgu_proj_w[i,t,:]); 0 fast-path when beta==0 ----
__global__ __launch_bounds__(256) void rowsum_kernel(const float* __restrict__ proj_w,
                                                     const float* __restrict__ sgu_ln_b,
                                                     float* __restrict__ R) {
    int wid  = (blockIdx.x * 256 + threadIdx.x) >> 6;  // 0..8191 (= layer*4096 + t)
    int lane = threadIdx.x & 63;
    int layer = wid >> 12;
    float beta = sgu_ln_b[layer];
    if (beta == 0.0f) {  // wave-uniform; inputs identical every call
        if (lane == 0) R[wid] = 0.0f;
        return;
    }
    const float* pr = proj_w + (size_t)wid * K_DIM;
    float s = 0.0f;
    for (int it = 0; it < 16; ++it) {
        float4 pv = *(const float4*)&pr[it * 256 + lane * 4];
        s += pv.x + pv.y + pv.z + pv.w;
    }
#pragma unroll
    for (int m = 1; m < 64; m <<= 1) s += __shfl_xor(s, m);
    if (lane == 0) R[wid] = s;
}

// ---------- K2: c[t]; also init d_out[t] = cls_b --------------------------------
__global__ __launch_bounds__(256) void c_kernel(const float* __restrict__ ln1_b,
                                                const float* __restrict__ cp1_w,
                                                const float* __restrict__ cp1_b,
                                                const float* __restrict__ sgu_ln_b,
                                                const float* __restrict__ sgu_proj_b,
                                                const float* __restrict__ cp2_w,
                                                const float* __restrict__ cp2_b,
                                                const float* __restrict__ cls_b,
                                                const float* __restrict__ R,
                                                float* __restrict__ c,
                                                float* __restrict__ out) {
    int t = blockIdx.x * 256 + threadIdx.x;  // 0..4095
    float cv = 0.0f;
#pragma unroll
    for (int i = 0; i < 2; ++i) {
        float alpha = gelu_exact(ln1_b[i] * cp1_w[i * 2 + 0] + cp1_b[i * 2 + 0]);
        float beta  = sgu_ln_b[i];
        float v     = beta * R[i * 4096 + t] + sgu_proj_b[i * 4096 + t];
        cv += alpha * v * cp2_w[i] + cp2_b[i];
    }
    c[t]   = cv;
    out[t] = cls_b[0];  // d_out is poisoned before every call -> re-init here
}

// ---------- K3: e[s] = sum_t c[t]*Pb[s,t] + pooler_b[s]  (Pb is bf16 copy) ------
__global__ __launch_bounds__(256) void e_kernel(const ushort* __restrict__ Pb,
                                                const float* __restrict__ c,
                                                const float* __restrict__ pooler_b,
                                                float* __restrict__ e) {
    int row  = blockIdx.x * 4 + (threadIdx.x >> 6);
    int lane = threadIdx.x & 63;
    const ushort* pr = Pb + (size_t)row * K_DIM;
    float s = 0.0f;
    for (int it = 0; it < 8; ++it) {
        int col = it * 512 + lane * 8;
        bf16x8 pv = *(const bf16x8*)&pr[col];
#pragma unroll
        for (int j = 0; j < 8; ++j) s += (float)pv[j] * c[col + j];
    }
#pragma unroll
    for (int m = 1; m < 64; m <<= 1) s += __shfl_xor(s, m);
    if (lane == 0) e[row] = s + pooler_b[row];
}

// ---------- K4: Y = x @ P^T (bf16 MFMA); fused gelu(Y+e)*cls_w row-reduce -------
// 128x128 block tile, BK=64, 4 waves (2x2), wave tile 64x64 of 16x16x32 MFMA.
// LDS layout (per 128x64 tile): byte(row, chunk) = row*128 + (chunk^(row&7))*16.
// global_load_lds forces LDS dst = lane*16, so the swizzle is applied to the
// GLOBAL chunk each staging thread fetches. Readers: chunk = (kk*4+g)^(lo&7)
// -> every quarter-wave phase spreads over all 32 banks at 2-way (free).
__global__ __launch_bounds__(256, 2) void gemm_kernel(const ushort* __restrict__ X,
                                                      const ushort* __restrict__ P,
                                                      const float* __restrict__ clsW,
                                                      const float* __restrict__ e,
                                                      float* __restrict__ accOut) {
    __shared__ __align__(16) ushort As[128 * 64];
    __shared__ __align__(16) ushort Bs[128 * 64];

    const int t = threadIdx.x;
    const int bCol = blockIdx.x, bRow = blockIdx.y;
    const int lane = t & 63, wv = t >> 6;
    const int g = lane >> 4, lo = lane & 15;
    const int wm = wv >> 1, wn = wv & 1;

    f32x4 zero4 = {0.f, 0.f, 0.f, 0.f};
    f32x4 acc[4][4];
#pragma unroll
    for (int mi = 0; mi < 4; ++mi)
#pragma unroll
        for (int ni = 0; ni < 4; ++ni) acc[mi][ni] = zero4;

    // staging: thread t -> LDS byte t*16 (+4KB per 32-row round).
    // LDS slot (t&7) of row (t>>3) holds GLOBAL chunk (t&7)^(row&7).
    const int sr = t >> 3;                      // 0..31
    const int cs = (t & 7) ^ (sr & 7);          // swizzled global 16B-chunk
    const ushort* gA = X + (size_t)(bRow * 128 + sr) * K_DIM + cs * 8;
    const ushort* gB = P + (size_t)(bCol * 128 + sr) * K_DIM + cs * 8;
    char* lA = (char*)As + t * 16;
    char* lB = (char*)Bs + t * 16;

    for (int k0 = 0; k0 < K_DIM; k0 += 64) {
        gld16(gA,              lA);
        gld16(gA + 32 * K_DIM, lA + 4096);
        gld16(gA + 64 * K_DIM, lA + 8192);
        gld16(gA + 96 * K_DIM, lA + 12288);
        gld16(gB,              lB);
        gld16(gB + 32 * K_DIM, lB + 4096);
        gld16(gB + 64 * K_DIM, lB + 8192);
        gld16(gB + 96 * K_DIM, lB + 12288);
        gA += 64;
        gB += 64;
        __syncthreads();  // vmcnt(0) drain: staging visible to all waves

#pragma unroll
        for (int kk = 0; kk < 2; ++kk) {
            const int ch = (((kk << 2) | g) ^ (lo & 7)) * 8;  // swizzled read chunk
            bf16x8 af[4], bfr[4];
#pragma unroll
            for (int mi = 0; mi < 4; ++mi) {
                int row = wm * 64 + mi * 16 + lo;
                af[mi] = *(const bf16x8*)&As[row * 64 + ch];
            }
#pragma unroll
            for (int ni = 0; ni < 4; ++ni) {
                int col = wn * 64 + ni * 16 + lo;
                bfr[ni] = *(const bf16x8*)&Bs[col * 64 + ch];
            }
#pragma unroll
            for (int mi = 0; mi < 4; ++mi)
#pragma unroll
                for (int ni = 0; ni < 4; ++ni)
                    acc[mi][ni] = __builtin_amdgcn_mfma_f32_16x16x32_bf16(af[mi], bfr[ni], acc[mi][ni], 0, 0, 0);
        }
        __syncthreads();
    }

    // Epilogue: C/D layout col=lane&15, row=(lane>>4)*4+reg (m89-verified).
    int sColBase = bCol * 128 + wn * 64 + lo;
    float eb[4], cw[4];
#pragma unroll
    for (int ni = 0; ni < 4; ++ni) {
        int s = sColBase + ni * 16;
        eb[ni] = e[s];
        cw[ni] = clsW[s];
    }
#pragma unroll
    for (int mi = 0; mi < 4; ++mi) {
        int rowBase = bRow * 128 + wm * 64 + mi * 16 + g * 4;
#pragma unroll
        for (int r = 0; r < 4; ++r) {
            float sum = 0.0f;
#pragma unroll
            for (int ni = 0; ni < 4; ++ni) {
                float y = acc[mi][ni][r] + eb[ni];
                sum += gelu_exact(y) * cw[ni];
            }
            sum += __shfl_xor(sum, 1);
            sum += __shfl_xor(sum, 2);
            sum += __shfl_xor(sum, 4);
            sum += __shfl_xor(sum, 8);
            if (lo == 0) atomicAdd(&accOut[rowBase + r], sum);
        }
    }
}

extern "C" void kernel_launch(void* const* d_in, const int* in_sizes, int n_in,
                              void* d_out, int out_size, void* d_ws, size_t ws_size,
                              hipStream_t stream) {
    const float* x          = (const float*)d_in[0];
    const float* ln1_b      = (const float*)d_in[2];
    const float* cp1_w      = (const float*)d_in[3];
    const float* cp1_b      = (const float*)d_in[4];
    const float* sgu_ln_b   = (const float*)d_in[6];
    const float* sgu_proj_w = (const float*)d_in[7];
    const float* sgu_proj_b = (const float*)d_in[8];
    const float* cp2_w      = (const float*)d_in[9];
    const float* cp2_b      = (const float*)d_in[10];
    const float* pooler_w   = (const float*)d_in[11];
    const float* pooler_b   = (const float*)d_in[12];
    const float* cls_w      = (const float*)d_in[13];
    const float* cls_b      = (const float*)d_in[14];

    // ws layout: xb (32MB bf16) | pb (32MB bf16) | c(16KB) | e(16KB) | R(32KB)
    ushort* xb = (ushort*)d_ws;                  // 4096*4096 bf16
    ushort* pb = xb + (size_t)K_DIM * K_DIM;     // 4096*4096 bf16
    float*  fs = (float*)(pb + (size_t)K_DIM * K_DIM);
    float* c_buf = fs;
    float* e_buf = fs + 4096;
    float* R     = fs + 8192;
    float* out   = (float*)d_out;

    cvt_kernel<<<8192, 256, 0, stream>>>(x, xb);
    cvt_kernel<<<8192, 256, 0, stream>>>(pooler_w, pb);
    rowsum_kernel<<<2048, 256, 0, stream>>>(sgu_proj_w, sgu_ln_b, R);
    c_kernel<<<16, 256, 0, stream>>>(ln1_b, cp1_w, cp1_b, sgu_ln_b, sgu_proj_b,
                                     cp2_w, cp2_b, cls_b, R, c_buf, out);
    e_kernel<<<1024, 256, 0, stream>>>(pb, c_buf, pooler_b, e_buf);
    gemm_kernel<<<dim3(32, 32), 256, 0, stream>>>(xb, pb, cls_w, e_buf, out);
}

// Round 4
// 403.956 us; speedup vs baseline: 1.0919x; 1.0208x over previous
//
#include <hip/hip_runtime.h>

// LatentClassifier collapse (all f32 I/O):
//   All depth-loop layernorms act on singleton axes -> LN(x) == bias exactly.
//   => h = x + c[t],  c[t] = sum_i alpha_i*w2_i*(beta_i*R_i[t] + sgu_proj_b[i,t]) + b2_i
//   out = (gelu((x+c) @ P^T + pooler_b)) @ cls_w^T + cls_b
//   c per-column => (x+c)@P^T = x@P^T + d[s], d[s] = sum_t c[t]*P[s,t]
// FP32 inputs, no fp32 MFMA -> convert x,P to bf16 once (ws), one 4096^3 bf16
// MFMA GEMM with fused gelu/cls epilogue atomicAdd into d_out.
//
// R3: conflicts fixed (XOR swizzle) -> 1025 TF, MfmaUtil 48.7%. Limiter is the
// LDS read pipe: 64x64 wave tile reads 192KB/CU/slab vs 1546cyc of MFMA.
// R4: 256x128 block tile, 4 waves of 128x64 -> FLOP/LDS-byte 32.8 -> 43.7,
// 2x MFMA per barrier, grid 512 = exactly 2 blocks/CU.

#define K_DIM 4096

typedef __bf16 bf16x8 __attribute__((ext_vector_type(8)));
typedef float f32x4 __attribute__((ext_vector_type(4)));

__device__ __forceinline__ ushort f2bf(float f) {
    unsigned int u = __float_as_uint(f);
    u = (u + 0x7fffu + ((u >> 16) & 1u)) >> 16;  // RTNE
    return (ushort)u;
}

__device__ __forceinline__ float gelu_exact(float x) {
    return 0.5f * x * (1.0f + erff(x * 0.70710678118654752440f));
}

__device__ __forceinline__ void gld16(const void* g, void* l) {
    __builtin_amdgcn_global_load_lds(
        (__attribute__((address_space(1))) void*)(g),
        (__attribute__((address_space(3))) void*)(l), 16, 0, 0);
}

// ---------- K0: f32 -> bf16 convert of x and pooler_w in one launch -------------
__global__ __launch_bounds__(256) void cvt2_kernel(const float* __restrict__ s0,
                                                   ushort* __restrict__ d0,
                                                   const float* __restrict__ s1,
                                                   ushort* __restrict__ d1) {
    int b = blockIdx.x;
    const float* src = (b < 8192) ? s0 : s1;
    ushort* dst = (b < 8192) ? d0 : d1;
    int i = (b & 8191) * 256 + threadIdx.x;  // 8 floats each
    const float4* s4 = (const float4*)src + (size_t)i * 2;
    float4 a = s4[0], c = s4[1];
    union { ushort u[8]; uint4 v; } r;
    r.u[0] = f2bf(a.x); r.u[1] = f2bf(a.y); r.u[2] = f2bf(a.z); r.u[3] = f2bf(a.w);
    r.u[4] = f2bf(c.x); r.u[5] = f2bf(c.y); r.u[6] = f2bf(c.z); r.u[7] = f2bf(c.w);
    ((uint4*)dst)[i] = r.v;
}

// ---------- K1: R_i[t] = rowsum(sgu_proj_w[i,t,:]); 0 fast-path when beta==0 ----
__global__ __launch_bounds__(256) void rowsum_kernel(const float* __restrict__ proj_w,
                                                     const float* __restrict__ sgu_ln_b,
                                                     float* __restrict__ R) {
    int wid  = (blockIdx.x * 256 + threadIdx.x) >> 6;  // 0..8191 (= layer*4096 + t)
    int lane = threadIdx.x & 63;
    int layer = wid >> 12;
    float beta = sgu_ln_b[layer];
    if (beta == 0.0f) {  // wave-uniform; inputs identical every call
        if (lane == 0) R[wid] = 0.0f;
        return;
    }
    const float* pr = proj_w + (size_t)wid * K_DIM;
    float s = 0.0f;
    for (int it = 0; it < 16; ++it) {
        float4 pv = *(const float4*)&pr[it * 256 + lane * 4];
        s += pv.x + pv.y + pv.z + pv.w;
    }
#pragma unroll
    for (int m = 1; m < 64; m <<= 1) s += __shfl_xor(s, m);
    if (lane == 0) R[wid] = s;
}

// ---------- K2: c[t]; also init d_out[t] = cls_b --------------------------------
__global__ __launch_bounds__(256) void c_kernel(const float* __restrict__ ln1_b,
                                                const float* __restrict__ cp1_w,
                                                const float* __restrict__ cp1_b,
                                                const float* __restrict__ sgu_ln_b,
                                                const float* __restrict__ sgu_proj_b,
                                                const float* __restrict__ cp2_w,
                                                const float* __restrict__ cp2_b,
                                                const float* __restrict__ cls_b,
                                                const float* __restrict__ R,
                                                float* __restrict__ c,
                                                float* __restrict__ out) {
    int t = blockIdx.x * 256 + threadIdx.x;  // 0..4095
    float cv = 0.0f;
#pragma unroll
    for (int i = 0; i < 2; ++i) {
        float alpha = gelu_exact(ln1_b[i] * cp1_w[i * 2 + 0] + cp1_b[i * 2 + 0]);
        float beta  = sgu_ln_b[i];
        float v     = beta * R[i * 4096 + t] + sgu_proj_b[i * 4096 + t];
        cv += alpha * v * cp2_w[i] + cp2_b[i];
    }
    c[t]   = cv;
    out[t] = cls_b[0];  // d_out poisoned before every call -> re-init here
}

// ---------- K3: e[s] = sum_t c[t]*Pb[s,t] + pooler_b[s]  (Pb = bf16 copy) -------
__global__ __launch_bounds__(256) void e_kernel(const ushort* __restrict__ Pb,
                                                const float* __restrict__ c,
                                                const float* __restrict__ pooler_b,
                                                float* __restrict__ e) {
    int row  = blockIdx.x * 4 + (threadIdx.x >> 6);
    int lane = threadIdx.x & 63;
    const ushort* pr = Pb + (size_t)row * K_DIM;
    float s = 0.0f;
    for (int it = 0; it < 8; ++it) {
        int col = it * 512 + lane * 8;
        bf16x8 pv = *(const bf16x8*)&pr[col];
#pragma unroll
        for (int j = 0; j < 8; ++j) s += (float)pv[j] * c[col + j];
    }
#pragma unroll
    for (int m = 1; m < 64; m <<= 1) s += __shfl_xor(s, m);
    if (lane == 0) e[row] = s + pooler_b[row];
}

// ---------- K4: Y = x @ P^T (bf16 MFMA); fused gelu(Y+e)*cls_w row-reduce -------
// 256x128 block tile, BK=64, 4 waves (2x2), wave tile 128x64 (8x4 frags of
// 16x16x32). LDS: byte(row,chunk) = row*128 + (chunk^(row&7))*16; swizzle is
// applied to the GLOBAL chunk on staging (global_load_lds dst = lane*16).
// Reads: chunk = (kk*4+g)^(lo&7) -> all phases 2-way on banks (free).
__global__ __launch_bounds__(256, 2) void gemm_kernel(const ushort* __restrict__ X,
                                                      const ushort* __restrict__ P,
                                                      const float* __restrict__ clsW,
                                                      const float* __restrict__ e,
                                                      float* __restrict__ accOut) {
    __shared__ __align__(16) ushort As[256 * 64];  // 32 KB
    __shared__ __align__(16) ushort Bs[128 * 64];  // 16 KB

    const int t = threadIdx.x;
    const int bCol = blockIdx.x, bRow = blockIdx.y;
    const int lane = t & 63, wv = t >> 6;
    const int g = lane >> 4, lo = lane & 15;
    const int wm = wv >> 1, wn = wv & 1;

    f32x4 zero4 = {0.f, 0.f, 0.f, 0.f};
    f32x4 acc[8][4];
#pragma unroll
    for (int mi = 0; mi < 8; ++mi)
#pragma unroll
        for (int ni = 0; ni < 4; ++ni) acc[mi][ni] = zero4;

    // staging: thread t -> rows (t>>3)+32*round, slot t&7 holds global chunk
    // (t&7)^(row&7); LDS dst byte = t*16 + round*4096.
    const int sr = t >> 3;                      // 0..31
    const int cs = (t & 7) ^ (sr & 7);          // swizzled global 16B-chunk
    const ushort* gA = X + (size_t)(bRow * 256 + sr) * K_DIM + cs * 8;
    const ushort* gB = P + (size_t)(bCol * 128 + sr) * K_DIM + cs * 8;
    char* lA = (char*)As + t * 16;
    char* lB = (char*)Bs + t * 16;

    for (int k0 = 0; k0 < K_DIM; k0 += 64) {
#pragma unroll
        for (int rd = 0; rd < 8; ++rd)
            gld16(gA + (size_t)(rd * 32) * K_DIM, lA + rd * 4096);
#pragma unroll
        for (int rd = 0; rd < 4; ++rd)
            gld16(gB + (size_t)(rd * 32) * K_DIM, lB + rd * 4096);
        gA += 64;
        gB += 64;
        __syncthreads();  // vmcnt(0) drain: staging visible to all waves

#pragma unroll
        for (int kk = 0; kk < 2; ++kk) {
            const int ch = (((kk << 2) | g) ^ (lo & 7)) * 8;  // swizzled chunk
            bf16x8 af[8], bfr[4];
#pragma unroll
            for (int mi = 0; mi < 8; ++mi) {
                int row = wm * 128 + mi * 16 + lo;
                af[mi] = *(const bf16x8*)&As[row * 64 + ch];
            }
#pragma unroll
            for (int ni = 0; ni < 4; ++ni) {
                int col = wn * 64 + ni * 16 + lo;
                bfr[ni] = *(const bf16x8*)&Bs[col * 64 + ch];
            }
#pragma unroll
            for (int mi = 0; mi < 8; ++mi)
#pragma unroll
                for (int ni = 0; ni < 4; ++ni)
                    acc[mi][ni] = __builtin_amdgcn_mfma_f32_16x16x32_bf16(af[mi], bfr[ni], acc[mi][ni], 0, 0, 0);
        }
        __syncthreads();
    }

    // Epilogue: C/D layout col=lane&15, row=(lane>>4)*4+reg (m89-verified).
    int sColBase = bCol * 128 + wn * 64 + lo;
    float eb[4], cw[4];
#pragma unroll
    for (int ni = 0; ni < 4; ++ni) {
        int s = sColBase + ni * 16;
        eb[ni] = e[s];
        cw[ni] = clsW[s];
    }
#pragma unroll
    for (int mi = 0; mi < 8; ++mi) {
        int rowBase = bRow * 256 + wm * 128 + mi * 16 + g * 4;
#pragma unroll
        for (int r = 0; r < 4; ++r) {
            float sum = 0.0f;
#pragma unroll
            for (int ni = 0; ni < 4; ++ni) {
                float y = acc[mi][ni][r] + eb[ni];
                sum += gelu_exact(y) * cw[ni];
            }
            sum += __shfl_xor(sum, 1);
            sum += __shfl_xor(sum, 2);
            sum += __shfl_xor(sum, 4);
            sum += __shfl_xor(sum, 8);
            if (lo == 0) atomicAdd(&accOut[rowBase + r], sum);
        }
    }
}

extern "C" void kernel_launch(void* const* d_in, const int* in_sizes, int n_in,
                              void* d_out, int out_size, void* d_ws, size_t ws_size,
                              hipStream_t stream) {
    const float* x          = (const float*)d_in[0];
    const float* ln1_b      = (const float*)d_in[2];
    const float* cp1_w      = (const float*)d_in[3];
    const float* cp1_b      = (const float*)d_in[4];
    const float* sgu_ln_b   = (const float*)d_in[6];
    const float* sgu_proj_w = (const float*)d_in[7];
    const float* sgu_proj_b = (const float*)d_in[8];
    const float* cp2_w      = (const float*)d_in[9];
    const float* cp2_b      = (const float*)d_in[10];
    const float* pooler_w   = (const float*)d_in[11];
    const float* pooler_b   = (const float*)d_in[12];
    const float* cls_w      = (const float*)d_in[13];
    const float* cls_b      = (const float*)d_in[14];

    // ws layout: xb (32MB bf16) | pb (32MB bf16) | c(16KB) | e(16KB) | R(32KB)
    ushort* xb = (ushort*)d_ws;                  // 4096*4096 bf16
    ushort* pb = xb + (size_t)K_DIM * K_DIM;     // 4096*4096 bf16
    float*  fs = (float*)(pb + (size_t)K_DIM * K_DIM);
    float* c_buf = fs;
    float* e_buf = fs + 4096;
    float* R     = fs + 8192;
    float* out   = (float*)d_out;

    cvt2_kernel<<<16384, 256, 0, stream>>>(x, xb, pooler_w, pb);
    rowsum_kernel<<<2048, 256, 0, stream>>>(sgu_proj_w, sgu_ln_b, R);
    c_kernel<<<16, 256, 0, stream>>>(ln1_b, cp1_w, cp1_b, sgu_ln_b, sgu_proj_b,
                                     cp2_w, cp2_b, cls_b, R, c_buf, out);
    e_kernel<<<1024, 256, 0, stream>>>(pb, c_buf, pooler_b, e_buf);
    gemm_kernel<<<dim3(32, 16), 256, 0, stream>>>(xb, pb, cls_w, e_buf, out);
}